// Round 9
// baseline (593.347 us; speedup 1.0000x reference)
//
#include <hip/hip_runtime.h>

typedef unsigned short u16;
typedef unsigned int   u32;
typedef __attribute__((ext_vector_type(8))) short short8;
typedef __attribute__((ext_vector_type(4))) float float4v;

// ---------- helpers ----------
__device__ __forceinline__ float bf2f(u16 u){ union{u32 i; float f;} c; c.i = ((u32)u) << 16; return c.f; }
__device__ __forceinline__ float bflo(u32 u){ union{u32 i; float f;} c; c.i = u << 16; return c.f; }
__device__ __forceinline__ float bfhi(u32 u){ union{u32 i; float f;} c; c.i = u & 0xFFFF0000u; return c.f; }
__device__ __forceinline__ u16 f2bf(float f){
  union{float f; u32 i;} c; c.f = f; u32 x = c.i;
  return (u16)((x + 0x7FFFu + ((x >> 16) & 1u)) >> 16);   // RNE
}
__device__ __forceinline__ u32 pack2(float a, float b){ return (u32)f2bf(a) | ((u32)f2bf(b) << 16); }

__device__ __forceinline__ void async16(const void* g, void* l){
  __builtin_amdgcn_global_load_lds((const __attribute__((address_space(1))) void*)g,
                                   (__attribute__((address_space(3))) void*)l, 16, 0, 0);
}

// ---------- prep: QHB rows 0-1535 = [wq_w; wk_w] bf16; bias[2304] fp32 (0 beyond 1536) ----------
__global__ void prep_qkw(const float* __restrict__ wq, const float* __restrict__ wk,
                         const float* __restrict__ wqb, const float* __restrict__ wkb,
                         u16* __restrict__ QHB, float* __restrict__ biasQH)
{
  int t = blockIdx.x * 256 + threadIdx.x;
  int stride = gridDim.x * 256;
  for (int i = t; i < 294912; i += stride) {
    float4 v = (i < 147456) ? ((const float4*)wq)[i] : ((const float4*)wk)[i - 147456];
    ushort4 o; o.x = f2bf(v.x); o.y = f2bf(v.y); o.z = f2bf(v.z); o.w = f2bf(v.w);
    ((ushort4*)QHB)[i] = o;
  }
  if (t < 768) biasQH[t] = wqb[t];
  else if (t < 1536) biasQH[t] = wkb[t - 768];
  else if (t < 2304) biasQH[t] = 0.f;
}

// gcn_w[l][d][o] -> l==0: QHB rows 1536+o ; l==1: gcnT1[o][d]   (fp32 -> bf16, transposed)
__global__ void prep_gcnT(const float* __restrict__ gcn, u16* __restrict__ QHB, u16* __restrict__ gcnT1)
{
  __shared__ float tile[32][33];
  int l = blockIdx.z;
  int d0 = blockIdx.y * 32, o0 = blockIdx.x * 32;
  int tx = threadIdx.x, ty = threadIdx.y;           // 32 x 8
  const float* src = gcn + (size_t)l * 589824;
  u16* dst = (l == 0) ? (QHB + (size_t)1536 * 768) : gcnT1;
  for (int i = 0; i < 32; i += 8) tile[ty + i][tx] = src[(size_t)(d0 + ty + i) * 768 + o0 + tx];
  __syncthreads();
  for (int i = 0; i < 32; i += 8) dst[(size_t)(o0 + ty + i) * 768 + d0 + tx] = f2bf(tile[tx][ty + i]);
}

// ---------- main GEMM: C[m][n] = sum_k A[m][k]*B[n][k] + bias[n] ----------
// 128x128 tile, BK=32. Grid: blockIdx.x = n-tile (fastest) so consecutive blocks
// share the A m-tile (L2-resident, kills the 5x A over-fetch seen in R8).
// AF32: A fp32, converted to bf16 in-register during staging.
template<bool AF32>
__global__ void __launch_bounds__(256) gemm_bt(const void* __restrict__ Aptr, const u16* __restrict__ Bw,
                                               const float* __restrict__ bias, u16* __restrict__ C,
                                               int M, int N, int K)
{
  __shared__ __attribute__((aligned(16))) u16 As[128 * 32];
  __shared__ __attribute__((aligned(16))) u16 Bs[128 * 32];
  int tid = threadIdx.x, lane = tid & 63, wid = tid >> 6;
  int wm = wid >> 1, wn = wid & 1;
  size_t n0 = (size_t)blockIdx.x * 128, m0 = (size_t)blockIdx.y * 128;

  float4v acc[4][4];
  for (int r = 0; r < 4; r++) for (int c = 0; c < 4; c++) acc[r][c] = (float4v){0.f, 0.f, 0.f, 0.f};

  int srow = 32 * wid + (lane >> 2);
  int sq   = (lane & 3) ^ ((lane >> 3) & 3);        // fetched chunk for slot lane&3
  const u16*  gB  = Bw + (n0 + srow) * (size_t)K + sq * 8;
  u16* lB = &Bs[1024 * wid];
  const float* gAf0 = AF32 ? ((const float*)Aptr + (m0 + srow) * (size_t)K + sq * 8) : nullptr;
  const float* gAf1 = AF32 ? ((const float*)Aptr + (m0 + srow + 16) * (size_t)K + sq * 8) : nullptr;
  const u16*  gA16 = AF32 ? nullptr : ((const u16*)Aptr + (m0 + srow) * (size_t)K + sq * 8);
  u16* lA = &As[1024 * wid];
  int wslot16 = srow * 32 + (lane & 3) * 8;          // u16 idx of this lane's 16B slot

  int l15 = lane & 15;
  int rs  = (lane >> 4) ^ ((lane >> 1) & 3);

  for (int kt = 0; kt < K; kt += 32) {
    if (AF32) {
      float4 f0 = *(const float4*)(gAf0 + kt);
      float4 f1 = *(const float4*)(gAf0 + kt + 4);
      float4 f2 = *(const float4*)(gAf1 + kt);
      float4 f3 = *(const float4*)(gAf1 + kt + 4);
      async16(gB + kt, lB);
      async16(gB + kt + (size_t)16 * K, lB + 512);
      uint4 o0 = { pack2(f0.x,f0.y), pack2(f0.z,f0.w), pack2(f1.x,f1.y), pack2(f1.z,f1.w) };
      uint4 o1 = { pack2(f2.x,f2.y), pack2(f2.z,f2.w), pack2(f3.x,f3.y), pack2(f3.z,f3.w) };
      *(uint4*)&As[wslot16]            = o0;
      *(uint4*)&As[wslot16 + 16 * 32]  = o1;
    } else {
      async16(gA16 + kt, lA);
      async16(gA16 + kt + (size_t)16 * K, lA + 512);
      async16(gB + kt, lB);
      async16(gB + kt + (size_t)16 * K, lB + 512);
    }
    __syncthreads();
    short8 af[4], bfr[4];
    for (int r = 0; r < 4; r++) af[r]  = *(const short8*)&As[(wm * 64 + r * 16 + l15) * 32 + rs * 8];
    for (int c = 0; c < 4; c++) bfr[c] = *(const short8*)&Bs[(wn * 64 + c * 16 + l15) * 32 + rs * 8];
    for (int r = 0; r < 4; r++)
      for (int c = 0; c < 4; c++)
        acc[r][c] = __builtin_amdgcn_mfma_f32_16x16x32_bf16(af[r], bfr[c], acc[r][c], 0, 0, 0);
    __syncthreads();
  }

  int quad = lane >> 4;
  for (int c = 0; c < 4; c++) {
    int n = (int)n0 + wn * 64 + c * 16 + l15;
    float bv = bias ? bias[n] : 0.f;
    for (int r = 0; r < 4; r++) {
      size_t mbase = m0 + wm * 64 + r * 16 + quad * 4;
      for (int t = 0; t < 4; t++)
        C[(mbase + t) * (size_t)N + n] = f2bf(acc[r][c][t] + bv);
    }
  }
}

// ================= fused per-graph adjacency kernels =================
// QH rows (stride 2304): [0,768)=Q, [768,1536)=K, [1536,2304)=H1.
// ch-loop software-pipelined: next chunk's H load issued between the barriers
// so its global latency overlaps this chunk's MFMA phase.

template<int NP>
__global__ void __launch_bounds__(512) fused_l1(const u16* __restrict__ QH,
                                                const float* __restrict__ lng, const float* __restrict__ lnb,
                                                u16* __restrict__ adjG, u16* __restrict__ X, int n)
{
  constexpr int ST = 72;
  constexpr int TPW = (NP == 64) ? 2 : 1;
  __shared__ __attribute__((aligned(16))) u16 adjb[NP * ST];
  __shared__ __attribute__((aligned(16))) u16 HT[64 * ST];
  __shared__ float rsum[NP];
  __shared__ float stats[NP][2];
  __shared__ float bc[NP][2];
  __shared__ float lg[768], lb[768];

  int g = blockIdx.x;
  int tid = threadIdx.x, lane = tid & 63, w = tid >> 6;
  int l15 = lane & 15, quad = lane >> 4;

  for (int i = tid; i < 768; i += 512) { lg[i] = lng[i]; lb[i] = lnb[i]; }
  if (tid < NP) { rsum[tid] = 0.f; stats[tid][0] = 0.f; stats[tid][1] = 0.f; }
  __syncthreads();

  // ---- stage 1: S = Q @ K^T, per-wave, direct from global ----
  int mt, nt0; bool s_act;
  if (NP == 64) { mt = w & 3; nt0 = (w >> 2) * 2; s_act = true; }
  else          { mt = w & 1; nt0 = w >> 1;       s_act = (w < 4); }

  int rowA = mt * 16 + l15;
  bool aok = rowA < n;
  const u16* pA  = QH + ((size_t)g * n + rowA) * 2304 + quad * 8;
  int rowB0 = (nt0) * 16 + l15, rowB1 = (nt0 + TPW - 1) * 16 + l15;
  bool b0ok = rowB0 < n, b1ok = rowB1 < n;
  const u16* pB0 = QH + ((size_t)g * n + rowB0) * 2304 + 768 + quad * 8;
  const u16* pB1 = QH + ((size_t)g * n + rowB1) * 2304 + 768 + quad * 8;

  float4v sacc[TPW];
  for (int j = 0; j < TPW; j++) sacc[j] = (float4v){0.f, 0.f, 0.f, 0.f};

  if (s_act) {
    for (int kt = 0; kt < 768; kt += 32) {
      uint4 av = {0,0,0,0}, bv0 = {0,0,0,0}, bv1 = {0,0,0,0};
      if (aok)  av  = *(const uint4*)(pA + kt);
      if (b0ok) bv0 = *(const uint4*)(pB0 + kt);
      if (TPW == 2 && b1ok) bv1 = *(const uint4*)(pB1 + kt);
      short8 a = *(short8*)&av;
      sacc[0] = __builtin_amdgcn_mfma_f32_16x16x32_bf16(a, *(short8*)&bv0, sacc[0], 0, 0, 0);
      if (TPW == 2)
        sacc[1] = __builtin_amdgcn_mfma_f32_16x16x32_bf16(a, *(short8*)&bv1, sacc[1], 0, 0, 0);
    }
    for (int t = 0; t < 4; t++) {
      float s = 0.f;
      for (int j = 0; j < TPW; j++) { float v = sacc[j][t]; s += v * v; }
      s += __shfl_xor(s, 1); s += __shfl_xor(s, 2); s += __shfl_xor(s, 4); s += __shfl_xor(s, 8);
      if (l15 == 0) atomicAdd(&rsum[mt * 16 + quad * 4 + t], s);
    }
  }
  __syncthreads();
  if (tid < NP) rsum[tid] = 1.0f / fmaxf(rsum[tid], 1e-12f);
  __syncthreads();
  if (s_act) {
    u16* gadj = adjG + (size_t)g * NP * NP;
    for (int j = 0; j < TPW; j++)
      for (int t = 0; t < 4; t++) {
        int row = mt * 16 + quad * 4 + t, col = (nt0 + j) * 16 + l15;
        float v = sacc[j][t];
        u16 b = f2bf(v * v * rsum[row]);
        adjb[row * ST + col] = b;
        gadj[row * NP + col] = b;
      }
  }

  // ---- stage 2: X = adj @ H1, pipelined 12 chunks of 64 d-cols ----
  int m2, nt20;
  if (NP == 64) { m2 = w & 3; nt20 = (w >> 2) * 2; }
  else          { m2 = w & 1; nt20 = w >> 1; }

  float4v xacc[12][TPW];
#pragma unroll
  for (int ch = 0; ch < 12; ch++) for (int j = 0; j < TPW; j++) xacc[ch][j] = (float4v){0.f,0.f,0.f,0.f};

  int hj  = tid & (NP - 1);
  int hseg= (NP == 64) ? w : ((tid >> 5) & 7);
  bool hact = (NP == 64) ? true : (tid < NP * 8);
  const u16* hbase = QH + ((size_t)g * n + hj) * 2304 + 1536 + hseg * 8;

  uint4 hv = {0,0,0,0};
  if (hact && hj < n) hv = *(const uint4*)(hbase);
#pragma unroll
  for (int ch = 0; ch < 12; ch++) {
    __syncthreads();                      // prev chunk's HT reads complete (covers adjb too, ch=0)
    if (hact) {
      const u16* ep = (const u16*)&hv;
      for (int i = 0; i < 8; i++) HT[(hseg * 8 + i) * ST + hj] = ep[i];
    }
    uint4 hnext = {0,0,0,0};
    if (ch < 11 && hact && hj < n) hnext = *(const uint4*)(hbase + (ch + 1) * 64);
    __syncthreads();
    for (int k = 0; k < NP / 32; k++) {
      short8 a = *(const short8*)&adjb[(m2 * 16 + l15) * ST + k * 32 + quad * 8];
      for (int j = 0; j < TPW; j++) {
        short8 b = *(const short8*)&HT[((nt20 + j) * 16 + l15) * ST + k * 32 + quad * 8];
        xacc[ch][j] = __builtin_amdgcn_mfma_f32_16x16x32_bf16(a, b, xacc[ch][j], 0, 0, 0);
      }
    }
    hv = hnext;
  }

  // ---- LN stats ----
  float ssum[4] = {0,0,0,0}, ssq[4] = {0,0,0,0};
#pragma unroll
  for (int ch = 0; ch < 12; ch++)
    for (int j = 0; j < TPW; j++)
      for (int t = 0; t < 4; t++) { float v = xacc[ch][j][t]; ssum[t] += v; ssq[t] += v * v; }
  for (int m = 1; m <= 8; m <<= 1)
    for (int t = 0; t < 4; t++) { ssum[t] += __shfl_xor(ssum[t], m); ssq[t] += __shfl_xor(ssq[t], m); }
  if (l15 == 0)
    for (int t = 0; t < 4; t++) {
      atomicAdd(&stats[m2 * 16 + quad * 4 + t][0], ssum[t]);
      atomicAdd(&stats[m2 * 16 + quad * 4 + t][1], ssq[t]);
    }
  __syncthreads();
  if (tid < NP) {
    float mu = stats[tid][0] * (1.f / 768.f);
    float var = stats[tid][1] * (1.f / 768.f) - mu * mu;
    bc[tid][0] = mu; bc[tid][1] = rsqrtf(fmaxf(var, 0.f) + 1e-5f);
  }
  __syncthreads();

#pragma unroll
  for (int ch = 0; ch < 12; ch++)
    for (int j = 0; j < TPW; j++)
      for (int t = 0; t < 4; t++) {
        int row = m2 * 16 + quad * 4 + t;
        if (row < n) {
          int d = ch * 64 + (nt20 + j) * 16 + l15;
          float v = fmaxf((xacc[ch][j][t] - bc[row][0]) * bc[row][1] * lg[d] + lb[d], 0.f);
          X[((size_t)g * n + row) * 768 + d] = f2bf(v);
        }
      }
}

template<int NP>
__global__ void __launch_bounds__(512) fused_l2(const u16* __restrict__ adjG, const u16* __restrict__ H,
                                                const float* __restrict__ lng, const float* __restrict__ lnb,
                                                u16* __restrict__ Xmean, int n, float inv)
{
  constexpr int ST = 72;
  constexpr int TPW = (NP == 64) ? 2 : 1;
  __shared__ __attribute__((aligned(16))) u16 adjb[NP * ST];
  __shared__ __attribute__((aligned(16))) u16 HT[64 * ST];
  __shared__ float stats[NP][2];
  __shared__ float bc[NP][2];
  __shared__ float colsum[768];
  __shared__ float lg[768], lb[768];

  int g = blockIdx.x;
  int tid = threadIdx.x, lane = tid & 63, w = tid >> 6;
  int l15 = lane & 15, quad = lane >> 4;

  for (int i = tid; i < 768; i += 512) { lg[i] = lng[i]; lb[i] = lnb[i]; colsum[i] = 0.f; }
  if (tid < NP) { stats[tid][0] = 0.f; stats[tid][1] = 0.f; }
  if (tid * 8 < NP * NP) {
    int row = (tid * 8) / NP, c0 = (tid * 8) % NP;
    uint4 v = *(const uint4*)(adjG + (size_t)g * NP * NP + row * NP + c0);
    *(uint4*)&adjb[row * ST + c0] = v;
  }

  int m2, nt20;
  if (NP == 64) { m2 = w & 3; nt20 = (w >> 2) * 2; }
  else          { m2 = w & 1; nt20 = w >> 1; }

  float4v xacc[12][TPW];
#pragma unroll
  for (int ch = 0; ch < 12; ch++) for (int j = 0; j < TPW; j++) xacc[ch][j] = (float4v){0.f,0.f,0.f,0.f};

  int hj  = tid & (NP - 1);
  int hseg= (NP == 64) ? w : ((tid >> 5) & 7);
  bool hact = (NP == 64) ? true : (tid < NP * 8);
  const u16* hbase = H + ((size_t)g * n + hj) * 768 + hseg * 8;

  uint4 hv = {0,0,0,0};
  if (hact && hj < n) hv = *(const uint4*)(hbase);
#pragma unroll
  for (int ch = 0; ch < 12; ch++) {
    __syncthreads();
    if (hact) {
      const u16* ep = (const u16*)&hv;
      for (int i = 0; i < 8; i++) HT[(hseg * 8 + i) * ST + hj] = ep[i];
    }
    uint4 hnext = {0,0,0,0};
    if (ch < 11 && hact && hj < n) hnext = *(const uint4*)(hbase + (ch + 1) * 64);
    __syncthreads();
    for (int k = 0; k < NP / 32; k++) {
      short8 a = *(const short8*)&adjb[(m2 * 16 + l15) * ST + k * 32 + quad * 8];
      for (int j = 0; j < TPW; j++) {
        short8 b = *(const short8*)&HT[((nt20 + j) * 16 + l15) * ST + k * 32 + quad * 8];
        xacc[ch][j] = __builtin_amdgcn_mfma_f32_16x16x32_bf16(a, b, xacc[ch][j], 0, 0, 0);
      }
    }
    hv = hnext;
  }

  float ssum[4] = {0,0,0,0}, ssq[4] = {0,0,0,0};
#pragma unroll
  for (int ch = 0; ch < 12; ch++)
    for (int j = 0; j < TPW; j++)
      for (int t = 0; t < 4; t++) { float v = xacc[ch][j][t]; ssum[t] += v; ssq[t] += v * v; }
  for (int m = 1; m <= 8; m <<= 1)
    for (int t = 0; t < 4; t++) { ssum[t] += __shfl_xor(ssum[t], m); ssq[t] += __shfl_xor(ssq[t], m); }
  if (l15 == 0)
    for (int t = 0; t < 4; t++) {
      atomicAdd(&stats[m2 * 16 + quad * 4 + t][0], ssum[t]);
      atomicAdd(&stats[m2 * 16 + quad * 4 + t][1], ssq[t]);
    }
  __syncthreads();
  if (tid < NP) {
    float mu = stats[tid][0] * (1.f / 768.f);
    float var = stats[tid][1] * (1.f / 768.f) - mu * mu;
    bc[tid][0] = mu; bc[tid][1] = rsqrtf(fmaxf(var, 0.f) + 1e-5f);
  }
  __syncthreads();

#pragma unroll
  for (int ch = 0; ch < 12; ch++)
    for (int j = 0; j < TPW; j++)
      for (int t = 0; t < 4; t++) {
        int row = m2 * 16 + quad * 4 + t;
        int d = ch * 64 + (nt20 + j) * 16 + l15;
        float v = fmaxf((xacc[ch][j][t] - bc[row][0]) * bc[row][1] * lg[d] + lb[d], 0.f);
        float vm = (row < n) ? v : 0.f;
        vm += __shfl_xor(vm, 16);
        vm += __shfl_xor(vm, 32);
        if (quad == 0) atomicAdd(&colsum[d], vm);
      }
  __syncthreads();
  if (tid < 384)
    ((u32*)Xmean)[(size_t)g * 384 + tid] = pack2(colsum[tid * 2] * inv, colsum[tid * 2 + 1] * inv);
}

// ---------- concat: y = [bf2f(Xm) ; fgs] fp32 (in d_out) ----------
__global__ void __launch_bounds__(384) concat_y(const u16* __restrict__ Xm,
                                                const float* __restrict__ fgs, float* __restrict__ yout)
{
  int b = blockIdx.x, tid = threadIdx.x;
  u32 u = ((const u32*)Xm)[(size_t)b * 384 + tid];
  int d0 = tid * 2;
  yout[(size_t)b * 1536 + d0]     = bflo(u);
  yout[(size_t)b * 1536 + d0 + 1] = bfhi(u);
  yout[(size_t)b * 1536 + 768 + d0]     = fgs[(size_t)b * 768 + d0];
  yout[(size_t)b * 1536 + 768 + d0 + 1] = fgs[(size_t)b * 768 + d0 + 1];
}

// ---------- classifier ----------
__global__ void __launch_bounds__(256) fc1_relu(const float* __restrict__ yout,
                                                const float* __restrict__ fc1w, const float* __restrict__ fc1b,
                                                float* __restrict__ h)
{
  int o = blockIdx.x * 4 + (threadIdx.x >> 6);
  int lane = threadIdx.x & 63;
  float acc[16];
  for (int b = 0; b < 16; b++) acc[b] = 0.f;
  const float4* wr = (const float4*)(fc1w + (size_t)o * 1536);
  for (int k4 = lane; k4 < 384; k4 += 64) {
    float4 wv = wr[k4];
    for (int b = 0; b < 16; b++) {
      float4 yv = ((const float4*)(yout + (size_t)b * 1536))[k4];
      acc[b] += wv.x * yv.x + wv.y * yv.y + wv.z * yv.z + wv.w * yv.w;
    }
  }
  for (int m = 1; m <= 32; m <<= 1)
    for (int b = 0; b < 16; b++) acc[b] += __shfl_xor(acc[b], m);
  if (lane < 16) h[(size_t)lane * 768 + o] = fmaxf(acc[lane] + fc1b[o], 0.f);
}

__global__ void __launch_bounds__(256) fc2_out(const float* __restrict__ h,
                                               const float* __restrict__ fc2w, const float* __restrict__ fc2b,
                                               float* __restrict__ logits)
{
  int o = blockIdx.x * 4 + (threadIdx.x >> 6);
  int lane = threadIdx.x & 63;
  float acc[16];
  for (int b = 0; b < 16; b++) acc[b] = 0.f;
  const float4* wr = (const float4*)(fc2w + (size_t)o * 768);
  for (int k4 = lane; k4 < 192; k4 += 64) {
    float4 wv = wr[k4];
    for (int b = 0; b < 16; b++) {
      float4 hv = ((const float4*)(h + (size_t)b * 768))[k4];
      acc[b] += wv.x * hv.x + wv.y * hv.y + wv.z * hv.z + wv.w * hv.w;
    }
  }
  for (int m = 1; m <= 32; m <<= 1)
    for (int b = 0; b < 16; b++) acc[b] += __shfl_xor(acc[b], m);
  if (lane < 16) logits[(size_t)lane * 400 + o] = acc[lane] + fc2b[o];
}

// ---------- launch ----------
extern "C" void kernel_launch(void* const* d_in, const int* in_sizes, int n_in,
                              void* d_out, int out_size, void* d_ws, size_t ws_size,
                              hipStream_t stream) {
  const float* feats = (const float*)d_in[0];
  const float* fgs   = (const float*)d_in[1];
  const float* wq_w  = (const float*)d_in[3];
  const float* wq_b  = (const float*)d_in[4];
  const float* wk_w  = (const float*)d_in[5];
  const float* wk_b  = (const float*)d_in[6];
  const float* gcn_w = (const float*)d_in[7];
  const float* ln_g  = (const float*)d_in[8];
  const float* ln_b  = (const float*)d_in[9];
  const float* fc1_w = (const float*)d_in[10];
  const float* fc1_b = (const float*)d_in[11];
  const float* fc2_w = (const float*)d_in[12];
  const float* fc2_b = (const float*)d_in[13];
  float* out  = (float*)d_out;
  float* yout = out + 16 * 400;               // y region: [16][1536] fp32

  char* ws = (char*)d_ws;
  size_t off = 0;
  auto alloc = [&](size_t b){ size_t r = off; off = (off + b + 255) & ~(size_t)255; return r; };
  // persistent (~10 MB)
  u16*  QHB    = (u16*) (ws + alloc((size_t)2304 * 768 * 2));    // [Wq;Wk;gcn0^T] bf16
  u16*  gcnT1  = (u16*) (ws + alloc((size_t)768 * 768 * 2));
  float* biasQH= (float*)(ws + alloc((size_t)2304 * 4));
  u16*  Xf     = (u16*) (ws + alloc((size_t)512 * 768 * 2));
  u16*  QHf    = (u16*) (ws + alloc((size_t)512 * 2304 * 2));
  u16*  X1f    = (u16*) (ws + alloc((size_t)512 * 768 * 2));
  u16*  H2f    = (u16*) (ws + alloc((size_t)512 * 768 * 2));
  u16*  adjFb  = (u16*) (ws + alloc((size_t)16 * 32 * 32 * 2));
  u16*  Xm     = (u16*) (ws + alloc((size_t)16 * 768 * 2));
  float* hbuf  = (float*)(ws + alloc((size_t)16 * 768 * 4));
  size_t base = off;

  // per-chunk: QHc [R][2304] + X1c [R][768] + adjGc [GC][64][64] bf16 (H2c aliases QHc)
  auto need = [&](int GC){
    size_t R = (size_t)GC * 50;
    return base + R * 2304 * 2 + 512 + R * 768 * 2 + 512 + (size_t)GC * 64 * 64 * 2 + 512;
  };
  int GC = 64;
  if (need(512) <= ws_size) GC = 512;
  else if (need(256) <= ws_size) GC = 256;
  else if (need(128) <= ws_size) GC = 128;
  int R = GC * 50;
  size_t off2 = base;
  auto alloc2 = [&](size_t b){ size_t r = off2; off2 = (off2 + b + 255) & ~(size_t)255; return r; };
  u16* QHc   = (u16*)(ws + alloc2((size_t)R * 2304 * 2));
  u16* X1c   = (u16*)(ws + alloc2((size_t)R * 768 * 2));
  u16* adjGc = (u16*)(ws + alloc2((size_t)GC * 64 * 64 * 2));
  u16* H2c   = QHc;                      // QH dead after fused_l1

  // prep
  prep_qkw<<<288, 256, 0, stream>>>(wq_w, wk_w, wq_b, wk_b, QHB, biasQH);
  prep_gcnT<<<dim3(24, 24, 2), dim3(32, 8), 0, stream>>>(gcn_w, QHB, gcnT1);

  // ---- object-level graph (512 graphs of n=50), chunked ----
  int nchunks = 512 / GC;
  for (int c = 0; c < nchunks; c++) {
    const float* fc = feats + (size_t)c * GC * 50 * 768;
    gemm_bt<true><<<dim3(18, R / 128), 256, 0, stream>>>(fc, QHB, biasQH, QHc, R, 2304, 768);
    fused_l1<64><<<GC, 512, 0, stream>>>(QHc, ln_g, ln_b, adjGc, X1c, 50);
    gemm_bt<false><<<dim3(6, R / 128), 256, 0, stream>>>(X1c, gcnT1, nullptr, H2c, R, 768, 768);
    fused_l2<64><<<GC, 512, 0, stream>>>(adjGc, H2c, ln_g + 768, ln_b + 768,
                                         Xf + (size_t)c * GC * 768, 50, 1.f / 50.f);
  }

  // ---- frame-level graph (16 graphs of n=32) ----
  gemm_bt<false><<<dim3(18, 4), 256, 0, stream>>>(Xf, QHB, biasQH, QHf, 512, 2304, 768);
  fused_l1<32><<<16, 512, 0, stream>>>(QHf, ln_g, ln_b, adjFb, X1f, 32);
  gemm_bt<false><<<dim3(6, 4), 256, 0, stream>>>(X1f, gcnT1, nullptr, H2f, 512, 768, 768);
  fused_l2<32><<<16, 512, 0, stream>>>(adjFb, H2f, ln_g + 768, ln_b + 768, Xm, 32, 1.f / 32.f);

  // ---- head ----
  concat_y<<<16, 384, 0, stream>>>(Xm, fgs, yout);
  fc1_relu<<<192, 256, 0, stream>>>(yout, fc1_w, fc1_b, hbuf);
  fc2_out<<<100, 256, 0, stream>>>(hbuf, fc2_w, fc2_b, out);
}